// Round 1
// baseline (432.067 us; speedup 1.0000x reference)
//
#include <hip/hip_runtime.h>
#include <hip/hip_bf16.h>

typedef __bf16 bf16x8 __attribute__((ext_vector_type(8)));
typedef float f32x4 __attribute__((ext_vector_type(4)));

#define M_TOK 16384   // 8 * 2048 tokens
#define CHUNK 64
#define NCHUNK 32     // 2048 / 64

// ---------------- fp32 -> bf16 bulk convert (vectorized) ----------------
__global__ __launch_bounds__(256) void f32_to_bf16_k(const float* __restrict__ in,
                                                     __hip_bfloat16* __restrict__ out, int n8) {
    int i = blockIdx.x * 256 + threadIdx.x;
    if (i >= n8) return;
    const f32x4* p4 = reinterpret_cast<const f32x4*>(in) + (size_t)i * 2;
    f32x4 a = p4[0], b = p4[1];
    union { __hip_bfloat16 h[8]; uint4 u; } o;
    o.h[0] = __float2bfloat16(a[0]); o.h[1] = __float2bfloat16(a[1]);
    o.h[2] = __float2bfloat16(a[2]); o.h[3] = __float2bfloat16(a[3]);
    o.h[4] = __float2bfloat16(b[0]); o.h[5] = __float2bfloat16(b[1]);
    o.h[6] = __float2bfloat16(b[2]); o.h[7] = __float2bfloat16(b[3]);
    *reinterpret_cast<uint4*>(out + (size_t)i * 8) = o.u;
}

// ---------------- bf16 MFMA GEMM:  out = epilogue(X[M,K] @ W[N,K]^T + bias) ----------------
// MODE 0: silu -> bf16 | 1: sigmoid -> bf16 | 3: (v)*aux -> bf16 | 4: f32 store
// MODE 5: f32 +=       | 6: f32 *= sigmoid(v)
template<int MODE>
__global__ __launch_bounds__(256)
void gemm_bt(const __hip_bfloat16* __restrict__ X, const __hip_bfloat16* __restrict__ W,
             const float* __restrict__ bias, const __hip_bfloat16* __restrict__ aux,
             float* __restrict__ Yf, __hip_bfloat16* __restrict__ Yb, int K, int N) {
    constexpr int PS = 72;                     // padded LDS row stride (bf16 elems)
    __shared__ __hip_bfloat16 As[128 * PS];
    __shared__ __hip_bfloat16 Bs[128 * PS];
    const int tid = threadIdx.x;
    const int m0 = blockIdx.y * 128, n0 = blockIdx.x * 128;
    const int wid = tid >> 6, lane = tid & 63;
    const int wm = wid >> 1, wn = wid & 1;
    const int lr = lane & 15, lg = lane >> 4;

    f32x4 acc[4][4] = {};

    for (int k0 = 0; k0 < K; k0 += 64) {
        #pragma unroll
        for (int j = 0; j < 4; ++j) {
            int q = tid + 256 * j;             // 0..1023 : 16B chunk id
            int row = q >> 3, cid = q & 7;
            *reinterpret_cast<bf16x8*>(&As[row * PS + cid * 8]) =
                *reinterpret_cast<const bf16x8*>(&X[(size_t)(m0 + row) * K + k0 + cid * 8]);
            *reinterpret_cast<bf16x8*>(&Bs[row * PS + cid * 8]) =
                *reinterpret_cast<const bf16x8*>(&W[(size_t)(n0 + row) * K + k0 + cid * 8]);
        }
        __syncthreads();
        #pragma unroll
        for (int kk = 0; kk < 2; ++kk) {
            bf16x8 af[4], bfr[4];
            #pragma unroll
            for (int m = 0; m < 4; ++m)
                af[m] = *reinterpret_cast<const bf16x8*>(&As[(wm*64 + m*16 + lr) * PS + kk*32 + lg*8]);
            #pragma unroll
            for (int n = 0; n < 4; ++n)
                bfr[n] = *reinterpret_cast<const bf16x8*>(&Bs[(wn*64 + n*16 + lr) * PS + kk*32 + lg*8]);
            #pragma unroll
            for (int m = 0; m < 4; ++m)
                #pragma unroll
                for (int n = 0; n < 4; ++n)
                    acc[m][n] = __builtin_amdgcn_mfma_f32_16x16x32_bf16(af[m], bfr[n], acc[m][n], 0, 0, 0);
        }
        __syncthreads();
    }

    #pragma unroll
    for (int m = 0; m < 4; ++m) {
        #pragma unroll
        for (int n = 0; n < 4; ++n) {
            #pragma unroll
            for (int r = 0; r < 4; ++r) {
                int row = m0 + wm*64 + m*16 + lg*4 + r;
                int col = n0 + wn*64 + n*16 + lr;
                size_t idx = (size_t)row * N + col;
                float v = acc[m][n][r] + bias[col];
                if constexpr (MODE == 0) {
                    float sg = 1.f / (1.f + __expf(-v));
                    Yb[idx] = __float2bfloat16(v * sg);
                } else if constexpr (MODE == 1) {
                    Yb[idx] = __float2bfloat16(1.f / (1.f + __expf(-v)));
                } else if constexpr (MODE == 3) {
                    Yb[idx] = __float2bfloat16(v * __bfloat162float(aux[idx]));
                } else if constexpr (MODE == 4) {
                    Yf[idx] = v;
                } else if constexpr (MODE == 5) {
                    Yf[idx] += v;
                } else if constexpr (MODE == 6) {
                    Yf[idx] = Yf[idx] * (1.f / (1.f + __expf(-v)));
                }
            }
        }
    }
}

// ---------------- 128x128x128 fp32 matmul (for A^2,A^4,...,A^64) ----------------
__global__ __launch_bounds__(128) void matmul128(const float* __restrict__ P,
                                                 const float* __restrict__ Q,
                                                 float* __restrict__ O) {
    int i = blockIdx.x, j = threadIdx.x;
    float acc = 0.f;
    #pragma unroll 8
    for (int k = 0; k < 128; ++k)
        acc = fmaf(P[i * 128 + k], Q[k * 128 + j], acc);
    O[i * 128 + j] = acc;
}

// ---------------- chunked scan phase 1: local chunk-end states (zero init) ----------------
__global__ __launch_bounds__(128) void ssm_phase1(const float* __restrict__ A,
                                                  const __hip_bfloat16* __restrict__ u,
                                                  float* __restrict__ E) {
    __shared__ float Al[128 * 132];
    __shared__ __align__(16) float hbuf[2][128];
    const int tid = threadIdx.x;
    #pragma unroll 8
    for (int r = 0; r < 128; ++r) Al[r * 132 + tid] = A[r * 128 + tid];
    hbuf[0][tid] = 0.f;
    __syncthreads();
    const int b = blockIdx.x >> 5, c = blockIdx.x & 31;
    const __hip_bfloat16* up = u + ((size_t)b * 2048 + c * CHUNK) * 128;
    const f32x4* Arow = reinterpret_cast<const f32x4*>(&Al[tid * 132]);
    int cur = 0;
    for (int t = 0; t < CHUNK; ++t) {
        const f32x4* hv = reinterpret_cast<const f32x4*>(hbuf[cur]);
        f32x4 s4 = {0.f, 0.f, 0.f, 0.f};
        #pragma unroll
        for (int k = 0; k < 32; ++k) s4 += Arow[k] * hv[k];
        float val = s4[0] + s4[1] + s4[2] + s4[3] + __bfloat162float(up[t * 128 + tid]);
        hbuf[cur ^ 1][tid] = val;
        __syncthreads();
        cur ^= 1;
    }
    E[(size_t)blockIdx.x * 128 + tid] = hbuf[cur][tid];
}

// ---------------- phase 2: sequential combine across chunks with A^64 ----------------
__global__ __launch_bounds__(1024) void ssm_phase2(const float* __restrict__ A64,
                                                   const float* __restrict__ E,
                                                   float* __restrict__ starts) {
    __shared__ float Al[128 * 132];
    __shared__ __align__(16) float st2[2][8][128];
    const int tid = threadIdx.x;
    for (int q = tid; q < 16384; q += 1024) Al[(q >> 7) * 132 + (q & 127)] = A64[q];
    const int b = tid >> 7, i = tid & 127;
    st2[0][b][i] = 0.f;
    __syncthreads();
    const f32x4* Arow = reinterpret_cast<const f32x4*>(&Al[i * 132]);
    int cur = 0;
    for (int c = 0; c < NCHUNK; ++c) {
        starts[((size_t)b * NCHUNK + c) * 128 + i] = st2[cur][b][i];
        const f32x4* hv = reinterpret_cast<const f32x4*>(st2[cur][b]);
        f32x4 s4 = {0.f, 0.f, 0.f, 0.f};
        #pragma unroll
        for (int k = 0; k < 32; ++k) s4 += Arow[k] * hv[k];
        float val = s4[0] + s4[1] + s4[2] + s4[3] + E[((size_t)b * NCHUNK + c) * 128 + i];
        st2[cur ^ 1][b][i] = val;
        __syncthreads();
        cur ^= 1;
    }
}

// ---------------- phase 3: re-run local scans from correct starts, emit hs (bf16) ----------------
__global__ __launch_bounds__(128) void ssm_phase3(const float* __restrict__ A,
                                                  const __hip_bfloat16* __restrict__ u,
                                                  const float* __restrict__ starts,
                                                  __hip_bfloat16* __restrict__ hs) {
    __shared__ float Al[128 * 132];
    __shared__ __align__(16) float hbuf[2][128];
    const int tid = threadIdx.x;
    #pragma unroll 8
    for (int r = 0; r < 128; ++r) Al[r * 132 + tid] = A[r * 128 + tid];
    hbuf[0][tid] = starts[(size_t)blockIdx.x * 128 + tid];
    __syncthreads();
    const int b = blockIdx.x >> 5, c = blockIdx.x & 31;
    const size_t tok0 = (size_t)b * 2048 + c * CHUNK;
    const __hip_bfloat16* up = u + tok0 * 128;
    const f32x4* Arow = reinterpret_cast<const f32x4*>(&Al[tid * 132]);
    int cur = 0;
    for (int t = 0; t < CHUNK; ++t) {
        const f32x4* hv = reinterpret_cast<const f32x4*>(hbuf[cur]);
        f32x4 s4 = {0.f, 0.f, 0.f, 0.f};
        #pragma unroll
        for (int k = 0; k < 32; ++k) s4 += Arow[k] * hv[k];
        float val = s4[0] + s4[1] + s4[2] + s4[3] + __bfloat162float(up[t * 128 + tid]);
        hs[(tok0 + t) * 128 + tid] = __float2bfloat16(val);
        hbuf[cur ^ 1][tid] = val;
        __syncthreads();
        cur ^= 1;
    }
}

// ---------------- host ----------------
extern "C" void kernel_launch(void* const* d_in, const int* in_sizes, int n_in,
                              void* d_out, int out_size, void* d_ws, size_t ws_size,
                              hipStream_t stream) {
    const float* x    = (const float*)d_in[0];
    const float* A    = (const float*)d_in[1];
    const float* B_w  = (const float*)d_in[2];
    const float* B_b  = (const float*)d_in[3];
    const float* C_w  = (const float*)d_in[4];
    const float* C_b  = (const float*)d_in[5];
    const float* D_w  = (const float*)d_in[6];
    const float* D_b  = (const float*)d_in[7];
    const float* s_w1 = (const float*)d_in[8];
    const float* s_b1 = (const float*)d_in[9];
    const float* s_w2 = (const float*)d_in[10];
    const float* s_b2 = (const float*)d_in[11];
    const float* g_w  = (const float*)d_in[12];
    const float* g_b  = (const float*)d_in[13];
    float* out = (float*)d_out;

    char* p = (char*)d_ws;
    auto alloc = [&](size_t n) { char* r = p; p += (n + 255) & ~(size_t)255; return r; };
    __hip_bfloat16* xb  = (__hip_bfloat16*)alloc((size_t)M_TOK * 1024 * 2);
    __hip_bfloat16* w1b = (__hip_bfloat16*)alloc(512 * 1024 * 2);
    __hip_bfloat16* w2b = (__hip_bfloat16*)alloc(128 * 512 * 2);
    __hip_bfloat16* Bwb = (__hip_bfloat16*)alloc(128 * 1024 * 2);
    __hip_bfloat16* Cwb = (__hip_bfloat16*)alloc(1024 * 128 * 2);
    __hip_bfloat16* Dwb = (__hip_bfloat16*)alloc(1024 * 1024 * 2);
    __hip_bfloat16* gwb = (__hip_bfloat16*)alloc(1024 * 1024 * 2);
    __hip_bfloat16* z1b = (__hip_bfloat16*)alloc((size_t)M_TOK * 512 * 2);
    __hip_bfloat16* sb  = (__hip_bfloat16*)alloc((size_t)M_TOK * 128 * 2);
    __hip_bfloat16* ub  = (__hip_bfloat16*)alloc((size_t)M_TOK * 128 * 2);
    __hip_bfloat16* hsb = (__hip_bfloat16*)alloc((size_t)M_TOK * 128 * 2);
    float* pa       = (float*)alloc(128 * 128 * 4);
    float* pb       = (float*)alloc(128 * 128 * 4);
    float* Ebuf     = (float*)alloc(256 * 128 * 4);
    float* startbuf = (float*)alloc(256 * 128 * 4);

    auto cvt = [&](const float* src, __hip_bfloat16* dst, int n) {
        int n8 = n / 8;
        f32_to_bf16_k<<<dim3((n8 + 255) / 256), dim3(256), 0, stream>>>(src, dst, n8);
    };
    cvt(x,    xb,  M_TOK * 1024);
    cvt(s_w1, w1b, 512 * 1024);
    cvt(s_w2, w2b, 128 * 512);
    cvt(B_w,  Bwb, 128 * 1024);
    cvt(C_w,  Cwb, 1024 * 128);
    cvt(D_w,  Dwb, 1024 * 1024);
    cvt(g_w,  gwb, 1024 * 1024);

    dim3 blk(256);
    // z1 = silu(x @ s_w1^T + s_b1)            [16384, 512]
    gemm_bt<0><<<dim3(4, 128), blk, 0, stream>>>(xb, w1b, s_b1, nullptr, nullptr, z1b, 1024, 512);
    // s = sigmoid(z1 @ s_w2^T + s_b2)          [16384, 128]
    gemm_bt<1><<<dim3(1, 128), blk, 0, stream>>>(z1b, w2b, s_b2, nullptr, nullptr, sb, 512, 128);
    // u = (x @ B_w^T + B_b) * s                [16384, 128]
    gemm_bt<3><<<dim3(1, 128), blk, 0, stream>>>(xb, Bwb, B_b, sb, nullptr, ub, 1024, 128);

    // A^64 by repeated squaring (fp32 exact)
    matmul128<<<128, 128, 0, stream>>>(A,  A,  pa);   // A^2
    matmul128<<<128, 128, 0, stream>>>(pa, pa, pb);   // A^4
    matmul128<<<128, 128, 0, stream>>>(pb, pb, pa);   // A^8
    matmul128<<<128, 128, 0, stream>>>(pa, pa, pb);   // A^16
    matmul128<<<128, 128, 0, stream>>>(pb, pb, pa);   // A^32
    matmul128<<<128, 128, 0, stream>>>(pa, pa, pb);   // A^64

    ssm_phase1<<<256, 128, 0, stream>>>(A, ub, Ebuf);
    ssm_phase2<<<1, 1024, 0, stream>>>(pb, Ebuf, startbuf);
    ssm_phase3<<<256, 128, 0, stream>>>(A, ub, startbuf, hsb);

    // out = x @ D_w^T + D_b ; += hs @ C_w^T + C_b ; *= sigmoid(x @ g_w^T + g_b)
    gemm_bt<4><<<dim3(8, 128), blk, 0, stream>>>(xb,  Dwb, D_b, nullptr, out, nullptr, 1024, 1024);
    gemm_bt<5><<<dim3(8, 128), blk, 0, stream>>>(hsb, Cwb, C_b, nullptr, out, nullptr, 128,  1024);
    gemm_bt<6><<<dim3(8, 128), blk, 0, stream>>>(xb,  gwb, g_b, nullptr, out, nullptr, 1024, 1024);
}

// Round 2
// 352.198 us; speedup vs baseline: 1.2268x; 1.2268x over previous
//
#include <hip/hip_runtime.h>
#include <hip/hip_bf16.h>

typedef __bf16 bf16x8 __attribute__((ext_vector_type(8)));
typedef float f32x4 __attribute__((ext_vector_type(4)));

#define M_TOK 16384   // 8 * 2048 tokens
#define CHUNK 64
#define NCHUNK 32     // 2048 / 64

__device__ __forceinline__ void gload16(const void* g, void* l) {
    __builtin_amdgcn_global_load_lds(
        (const __attribute__((address_space(1))) void*)g,
        (__attribute__((address_space(3))) void*)l, 16, 0, 0);
}

__device__ __forceinline__ float sigmoidf_(float v) { return 1.f / (1.f + __expf(-v)); }

// ---------------- fp32 -> bf16 bulk convert (vectorized) ----------------
__global__ __launch_bounds__(256) void f32_to_bf16_k(const float* __restrict__ in,
                                                     __hip_bfloat16* __restrict__ out, int n8) {
    int i = blockIdx.x * 256 + threadIdx.x;
    if (i >= n8) return;
    const f32x4* p4 = reinterpret_cast<const f32x4*>(in) + (size_t)i * 2;
    f32x4 a = p4[0], b = p4[1];
    union { __hip_bfloat16 h[8]; uint4 u; } o;
    o.h[0] = __float2bfloat16(a[0]); o.h[1] = __float2bfloat16(a[1]);
    o.h[2] = __float2bfloat16(a[2]); o.h[3] = __float2bfloat16(a[3]);
    o.h[4] = __float2bfloat16(b[0]); o.h[5] = __float2bfloat16(b[1]);
    o.h[6] = __float2bfloat16(b[2]); o.h[7] = __float2bfloat16(b[3]);
    *reinterpret_cast<uint4*>(out + (size_t)i * 8) = o.u;
}

// ---------------- z1 = silu(x @ s_w1^T + s_b1)  [16384,512], m97-style ----------------
__global__ __launch_bounds__(256)
void gemm_silu(const __hip_bfloat16* __restrict__ X, const __hip_bfloat16* __restrict__ W,
               const float* __restrict__ bias, __hip_bfloat16* __restrict__ Yb) {
    constexpr int K = 1024, N = 512;
    __shared__ __align__(16) __hip_bfloat16 As[128 * 64];
    __shared__ __align__(16) __hip_bfloat16 Bs[128 * 64];
    // XCD-bijective swizzle, nwg=512
    const int orig = blockIdx.x;
    const int v = (orig & 7) * 64 + (orig >> 3);
    const int mi = v >> 2, ni = v & 3;
    const int m0 = mi * 128, n0 = ni * 128;
    const int tid = threadIdx.x;
    const int wid = tid >> 6, lane = tid & 63;
    const int wm = wid >> 1, wn = wid & 1;
    const int lr = lane & 15, lg = lane >> 4;
    const int srow = tid >> 3, sc8 = tid & 7;   // staging row/chunk base

    f32x4 acc[4][4] = {};
    for (int k0 = 0; k0 < K; k0 += 64) {
        __syncthreads();
        #pragma unroll
        for (int j = 0; j < 4; ++j) {
            int row = srow + j * 32, q = tid + 256 * j;
            gload16(&X[(size_t)(m0 + row) * K + k0 + sc8 * 8], &As[q * 8]);
            gload16(&W[(size_t)(n0 + row) * K + k0 + sc8 * 8], &Bs[q * 8]);
        }
        __syncthreads();
        #pragma unroll
        for (int kk = 0; kk < 2; ++kk) {
            bf16x8 af[4], bfr[4];
            #pragma unroll
            for (int m = 0; m < 4; ++m)
                af[m] = *reinterpret_cast<const bf16x8*>(&As[(wm*64 + m*16 + lr) * 64 + kk*32 + lg*8]);
            #pragma unroll
            for (int n = 0; n < 4; ++n)
                bfr[n] = *reinterpret_cast<const bf16x8*>(&Bs[(wn*64 + n*16 + lr) * 64 + kk*32 + lg*8]);
            #pragma unroll
            for (int m = 0; m < 4; ++m)
                #pragma unroll
                for (int n = 0; n < 4; ++n)
                    acc[m][n] = __builtin_amdgcn_mfma_f32_16x16x32_bf16(af[m], bfr[n], acc[m][n], 0, 0, 0);
        }
    }
    #pragma unroll
    for (int m = 0; m < 4; ++m)
        #pragma unroll
        for (int n = 0; n < 4; ++n)
            #pragma unroll
            for (int r = 0; r < 4; ++r) {
                int row = m0 + wm*64 + m*16 + lg*4 + r;
                int col = n0 + wn*64 + n*16 + lr;
                float val = acc[m][n][r] + bias[col];
                Yb[(size_t)row * N + col] = __float2bfloat16(val * sigmoidf_(val));
            }
}

// ---------------- u = (x@B_w^T + B_b) * sigmoid(z1@s_w2^T + s_b2)   [16384,128] ----------------
// 64x128 tile, fused: no s buffer materialized.
__global__ __launch_bounds__(256)
void gemm_u(const __hip_bfloat16* __restrict__ Z1, const __hip_bfloat16* __restrict__ W2,
            const float* __restrict__ b2,
            const __hip_bfloat16* __restrict__ X, const __hip_bfloat16* __restrict__ Bw,
            const float* __restrict__ Bb, __hip_bfloat16* __restrict__ U) {
    __shared__ __align__(16) __hip_bfloat16 As[64 * 64];
    __shared__ __align__(16) __hip_bfloat16 Bs[128 * 64];
    const int orig = blockIdx.x;                 // nwg = 256
    const int v = (orig & 7) * 32 + (orig >> 3);
    const int m0 = v * 64;
    const int tid = threadIdx.x;
    const int wid = tid >> 6, lane = tid & 63;
    const int wm = wid >> 1, wn = wid & 1;
    const int lr = lane & 15, lg = lane >> 4;
    const int srow = tid >> 3, sc8 = tid & 7;

    f32x4 accS[2][4] = {};
    // phase 1: z1 @ s_w2^T  (K=512)
    for (int k0 = 0; k0 < 512; k0 += 64) {
        __syncthreads();
        #pragma unroll
        for (int j = 0; j < 2; ++j) {
            int row = srow + j * 32, q = tid + 256 * j;
            gload16(&Z1[(size_t)(m0 + row) * 512 + k0 + sc8 * 8], &As[q * 8]);
        }
        #pragma unroll
        for (int j = 0; j < 4; ++j) {
            int row = srow + j * 32, q = tid + 256 * j;
            gload16(&W2[(size_t)row * 512 + k0 + sc8 * 8], &Bs[q * 8]);
        }
        __syncthreads();
        #pragma unroll
        for (int kk = 0; kk < 2; ++kk) {
            bf16x8 af[2], bfr[4];
            #pragma unroll
            for (int m = 0; m < 2; ++m)
                af[m] = *reinterpret_cast<const bf16x8*>(&As[(wm*32 + m*16 + lr) * 64 + kk*32 + lg*8]);
            #pragma unroll
            for (int n = 0; n < 4; ++n)
                bfr[n] = *reinterpret_cast<const bf16x8*>(&Bs[(wn*64 + n*16 + lr) * 64 + kk*32 + lg*8]);
            #pragma unroll
            for (int m = 0; m < 2; ++m)
                #pragma unroll
                for (int n = 0; n < 4; ++n)
                    accS[m][n] = __builtin_amdgcn_mfma_f32_16x16x32_bf16(af[m], bfr[n], accS[m][n], 0, 0, 0);
        }
    }
    // sigmoid in-register
    #pragma unroll
    for (int m = 0; m < 2; ++m)
        #pragma unroll
        for (int n = 0; n < 4; ++n)
            #pragma unroll
            for (int r = 0; r < 4; ++r) {
                int col = wn*64 + n*16 + lr;
                accS[m][n][r] = sigmoidf_(accS[m][n][r] + b2[col]);
            }
    // phase 2: x @ B_w^T  (K=1024)
    f32x4 accU[2][4] = {};
    for (int k0 = 0; k0 < 1024; k0 += 64) {
        __syncthreads();
        #pragma unroll
        for (int j = 0; j < 2; ++j) {
            int row = srow + j * 32, q = tid + 256 * j;
            gload16(&X[(size_t)(m0 + row) * 1024 + k0 + sc8 * 8], &As[q * 8]);
        }
        #pragma unroll
        for (int j = 0; j < 4; ++j) {
            int row = srow + j * 32, q = tid + 256 * j;
            gload16(&Bw[(size_t)row * 1024 + k0 + sc8 * 8], &Bs[q * 8]);
        }
        __syncthreads();
        #pragma unroll
        for (int kk = 0; kk < 2; ++kk) {
            bf16x8 af[2], bfr[4];
            #pragma unroll
            for (int m = 0; m < 2; ++m)
                af[m] = *reinterpret_cast<const bf16x8*>(&As[(wm*32 + m*16 + lr) * 64 + kk*32 + lg*8]);
            #pragma unroll
            for (int n = 0; n < 4; ++n)
                bfr[n] = *reinterpret_cast<const bf16x8*>(&Bs[(wn*64 + n*16 + lr) * 64 + kk*32 + lg*8]);
            #pragma unroll
            for (int m = 0; m < 2; ++m)
                #pragma unroll
                for (int n = 0; n < 4; ++n)
                    accU[m][n] = __builtin_amdgcn_mfma_f32_16x16x32_bf16(af[m], bfr[n], accU[m][n], 0, 0, 0);
        }
    }
    #pragma unroll
    for (int m = 0; m < 2; ++m)
        #pragma unroll
        for (int n = 0; n < 4; ++n)
            #pragma unroll
            for (int r = 0; r < 4; ++r) {
                int row = m0 + wm*32 + m*16 + lg*4 + r;
                int col = wn*64 + n*16 + lr;
                float uval = (accU[m][n][r] + Bb[col]) * accS[m][n][r];
                U[(size_t)row * 128 + col] = __float2bfloat16(uval);
            }
}

// ---------------- fused output: out = (x@D^T + Db + hs@C^T + Cb) * sigmoid(x@g^T + gb) ----------------
__global__ __launch_bounds__(256)
void gemm_out(const __hip_bfloat16* __restrict__ X, const __hip_bfloat16* __restrict__ Dw,
              const __hip_bfloat16* __restrict__ Gw, const __hip_bfloat16* __restrict__ HS,
              const __hip_bfloat16* __restrict__ Cw,
              const float* __restrict__ Db, const float* __restrict__ Cb,
              const float* __restrict__ Gb, float* __restrict__ out) {
    __shared__ __align__(16) __hip_bfloat16 Xs[128 * 64];
    __shared__ __align__(16) __hip_bfloat16 Ds[128 * 64];
    __shared__ __align__(16) __hip_bfloat16 Gs[128 * 64];
    // nwg = 1024; XCD gets contiguous 128 virtual ids; within XCD: 16 row panels x 8 col panels
    const int orig = blockIdx.x;
    const int v = (orig & 7) * 128 + (orig >> 3);
    const int mi = v >> 3, ni = v & 7;
    const int m0 = mi * 128, n0 = ni * 128;
    const int tid = threadIdx.x;
    const int wid = tid >> 6, lane = tid & 63;
    const int wm = wid >> 1, wn = wid & 1;
    const int lr = lane & 15, lg = lane >> 4;
    const int srow = tid >> 3, sc8 = tid & 7;

    f32x4 accY[4][4] = {};
    f32x4 accG[4][4] = {};

    // main K-loop over x vs (D_w, g_w)
    for (int k0 = 0; k0 < 1024; k0 += 64) {
        __syncthreads();
        #pragma unroll
        for (int j = 0; j < 4; ++j) {
            int row = srow + j * 32, q = tid + 256 * j;
            gload16(&X [(size_t)(m0 + row) * 1024 + k0 + sc8 * 8], &Xs[q * 8]);
            gload16(&Dw[(size_t)(n0 + row) * 1024 + k0 + sc8 * 8], &Ds[q * 8]);
            gload16(&Gw[(size_t)(n0 + row) * 1024 + k0 + sc8 * 8], &Gs[q * 8]);
        }
        __syncthreads();
        #pragma unroll
        for (int kk = 0; kk < 2; ++kk) {
            bf16x8 af[4];
            #pragma unroll
            for (int m = 0; m < 4; ++m)
                af[m] = *reinterpret_cast<const bf16x8*>(&Xs[(wm*64 + m*16 + lr) * 64 + kk*32 + lg*8]);
            #pragma unroll
            for (int n = 0; n < 4; ++n) {
                bf16x8 dfr = *reinterpret_cast<const bf16x8*>(&Ds[(wn*64 + n*16 + lr) * 64 + kk*32 + lg*8]);
                bf16x8 gfr = *reinterpret_cast<const bf16x8*>(&Gs[(wn*64 + n*16 + lr) * 64 + kk*32 + lg*8]);
                #pragma unroll
                for (int m = 0; m < 4; ++m)
                    accY[m][n] = __builtin_amdgcn_mfma_f32_16x16x32_bf16(af[m], dfr, accY[m][n], 0, 0, 0);
                #pragma unroll
                for (int m = 0; m < 4; ++m)
                    accG[m][n] = __builtin_amdgcn_mfma_f32_16x16x32_bf16(af[m], gfr, accG[m][n], 0, 0, 0);
            }
        }
    }
    // C-phase: hs @ C_w^T (K=128) accumulates into accY
    for (int k0 = 0; k0 < 128; k0 += 64) {
        __syncthreads();
        #pragma unroll
        for (int j = 0; j < 4; ++j) {
            int row = srow + j * 32, q = tid + 256 * j;
            gload16(&HS[(size_t)(m0 + row) * 128 + k0 + sc8 * 8], &Xs[q * 8]);
            gload16(&Cw[(size_t)(n0 + row) * 128 + k0 + sc8 * 8], &Ds[q * 8]);
        }
        __syncthreads();
        #pragma unroll
        for (int kk = 0; kk < 2; ++kk) {
            bf16x8 af[4], bfr[4];
            #pragma unroll
            for (int m = 0; m < 4; ++m)
                af[m] = *reinterpret_cast<const bf16x8*>(&Xs[(wm*64 + m*16 + lr) * 64 + kk*32 + lg*8]);
            #pragma unroll
            for (int n = 0; n < 4; ++n)
                bfr[n] = *reinterpret_cast<const bf16x8*>(&Ds[(wn*64 + n*16 + lr) * 64 + kk*32 + lg*8]);
            #pragma unroll
            for (int m = 0; m < 4; ++m)
                #pragma unroll
                for (int n = 0; n < 4; ++n)
                    accY[m][n] = __builtin_amdgcn_mfma_f32_16x16x32_bf16(af[m], bfr[n], accY[m][n], 0, 0, 0);
        }
    }
    // epilogue
    #pragma unroll
    for (int m = 0; m < 4; ++m)
        #pragma unroll
        for (int n = 0; n < 4; ++n)
            #pragma unroll
            for (int r = 0; r < 4; ++r) {
                int row = m0 + wm*64 + m*16 + lg*4 + r;
                int col = n0 + wn*64 + n*16 + lr;
                float y = accY[m][n][r] + Db[col] + Cb[col];
                float g = accG[m][n][r] + Gb[col];
                out[(size_t)row * 1024 + col] = y * sigmoidf_(g);
            }
}

// ---------------- 128x128x128 fp32 matmul (for A^2,A^4,...,A^64) ----------------
__global__ __launch_bounds__(128) void matmul128(const float* __restrict__ P,
                                                 const float* __restrict__ Q,
                                                 float* __restrict__ O) {
    int i = blockIdx.x, j = threadIdx.x;
    float acc = 0.f;
    #pragma unroll 8
    for (int k = 0; k < 128; ++k)
        acc = fmaf(P[i * 128 + k], Q[k * 128 + j], acc);
    O[i * 128 + j] = acc;
}

// ---------------- chunked scan phase 1: local chunk-end states (zero init) ----------------
__global__ __launch_bounds__(128) void ssm_phase1(const float* __restrict__ A,
                                                  const __hip_bfloat16* __restrict__ u,
                                                  float* __restrict__ E) {
    __shared__ float Al[128 * 132];
    __shared__ __align__(16) float hbuf[2][128];
    const int tid = threadIdx.x;
    #pragma unroll 8
    for (int r = 0; r < 128; ++r) Al[r * 132 + tid] = A[r * 128 + tid];
    hbuf[0][tid] = 0.f;
    __syncthreads();
    const int b = blockIdx.x >> 5, c = blockIdx.x & 31;
    const __hip_bfloat16* up = u + ((size_t)b * 2048 + c * CHUNK) * 128;
    const f32x4* Arow = reinterpret_cast<const f32x4*>(&Al[tid * 132]);
    int cur = 0;
    for (int t = 0; t < CHUNK; ++t) {
        const f32x4* hv = reinterpret_cast<const f32x4*>(hbuf[cur]);
        f32x4 s4 = {0.f, 0.f, 0.f, 0.f};
        #pragma unroll
        for (int k = 0; k < 32; ++k) s4 += Arow[k] * hv[k];
        float val = s4[0] + s4[1] + s4[2] + s4[3] + __bfloat162float(up[t * 128 + tid]);
        hbuf[cur ^ 1][tid] = val;
        __syncthreads();
        cur ^= 1;
    }
    E[(size_t)blockIdx.x * 128 + tid] = hbuf[cur][tid];
}

// ---------------- phase 2: per-batch sequential combine across chunks with A^64 ----------------
__global__ __launch_bounds__(128) void ssm_phase2(const float* __restrict__ A64,
                                                  const float* __restrict__ E,
                                                  float* __restrict__ starts) {
    __shared__ float Al[128 * 132];
    __shared__ __align__(16) float st[2][128];
    const int tid = threadIdx.x;
    const int b = blockIdx.x;     // 8 blocks, one per batch
    #pragma unroll 8
    for (int r = 0; r < 128; ++r) Al[r * 132 + tid] = A64[r * 128 + tid];
    st[0][tid] = 0.f;
    __syncthreads();
    const f32x4* Arow = reinterpret_cast<const f32x4*>(&Al[tid * 132]);
    int cur = 0;
    for (int c = 0; c < NCHUNK; ++c) {
        starts[((size_t)b * NCHUNK + c) * 128 + tid] = st[cur][tid];
        const f32x4* hv = reinterpret_cast<const f32x4*>(st[cur]);
        f32x4 s4 = {0.f, 0.f, 0.f, 0.f};
        #pragma unroll
        for (int k = 0; k < 32; ++k) s4 += Arow[k] * hv[k];
        float val = s4[0] + s4[1] + s4[2] + s4[3] + E[((size_t)b * NCHUNK + c) * 128 + tid];
        st[cur ^ 1][tid] = val;
        __syncthreads();
        cur ^= 1;
    }
}

// ---------------- phase 3: re-run local scans from correct starts, emit hs (bf16) ----------------
__global__ __launch_bounds__(128) void ssm_phase3(const float* __restrict__ A,
                                                  const __hip_bfloat16* __restrict__ u,
                                                  const float* __restrict__ starts,
                                                  __hip_bfloat16* __restrict__ hs) {
    __shared__ float Al[128 * 132];
    __shared__ __align__(16) float hbuf[2][128];
    const int tid = threadIdx.x;
    #pragma unroll 8
    for (int r = 0; r < 128; ++r) Al[r * 132 + tid] = A[r * 128 + tid];
    hbuf[0][tid] = starts[(size_t)blockIdx.x * 128 + tid];
    __syncthreads();
    const int b = blockIdx.x >> 5, c = blockIdx.x & 31;
    const size_t tok0 = (size_t)b * 2048 + c * CHUNK;
    const __hip_bfloat16* up = u + tok0 * 128;
    const f32x4* Arow = reinterpret_cast<const f32x4*>(&Al[tid * 132]);
    int cur = 0;
    for (int t = 0; t < CHUNK; ++t) {
        const f32x4* hv = reinterpret_cast<const f32x4*>(hbuf[cur]);
        f32x4 s4 = {0.f, 0.f, 0.f, 0.f};
        #pragma unroll
        for (int k = 0; k < 32; ++k) s4 += Arow[k] * hv[k];
        float val = s4[0] + s4[1] + s4[2] + s4[3] + __bfloat162float(up[t * 128 + tid]);
        hs[(tok0 + t) * 128 + tid] = __float2bfloat16(val);
        hbuf[cur ^ 1][tid] = val;
        __syncthreads();
        cur ^= 1;
    }
}

// ---------------- host ----------------
extern "C" void kernel_launch(void* const* d_in, const int* in_sizes, int n_in,
                              void* d_out, int out_size, void* d_ws, size_t ws_size,
                              hipStream_t stream) {
    const float* x    = (const float*)d_in[0];
    const float* A    = (const float*)d_in[1];
    const float* B_w  = (const float*)d_in[2];
    const float* B_b  = (const float*)d_in[3];
    const float* C_w  = (const float*)d_in[4];
    const float* C_b  = (const float*)d_in[5];
    const float* D_w  = (const float*)d_in[6];
    const float* D_b  = (const float*)d_in[7];
    const float* s_w1 = (const float*)d_in[8];
    const float* s_b1 = (const float*)d_in[9];
    const float* s_w2 = (const float*)d_in[10];
    const float* s_b2 = (const float*)d_in[11];
    const float* g_w  = (const float*)d_in[12];
    const float* g_b  = (const float*)d_in[13];
    float* out = (float*)d_out;

    char* p = (char*)d_ws;
    auto alloc = [&](size_t n) { char* r = p; p += (n + 255) & ~(size_t)255; return r; };
    __hip_bfloat16* xb  = (__hip_bfloat16*)alloc((size_t)M_TOK * 1024 * 2);
    __hip_bfloat16* w1b = (__hip_bfloat16*)alloc(512 * 1024 * 2);
    __hip_bfloat16* w2b = (__hip_bfloat16*)alloc(128 * 512 * 2);
    __hip_bfloat16* Bwb = (__hip_bfloat16*)alloc(128 * 1024 * 2);
    __hip_bfloat16* Cwb = (__hip_bfloat16*)alloc(1024 * 128 * 2);
    __hip_bfloat16* Dwb = (__hip_bfloat16*)alloc(1024 * 1024 * 2);
    __hip_bfloat16* gwb = (__hip_bfloat16*)alloc(1024 * 1024 * 2);
    __hip_bfloat16* z1b = (__hip_bfloat16*)alloc((size_t)M_TOK * 512 * 2);
    __hip_bfloat16* ub  = (__hip_bfloat16*)alloc((size_t)M_TOK * 128 * 2);
    __hip_bfloat16* hsb = (__hip_bfloat16*)alloc((size_t)M_TOK * 128 * 2);
    float* pa       = (float*)alloc(128 * 128 * 4);
    float* pb       = (float*)alloc(128 * 128 * 4);
    float* Ebuf     = (float*)alloc(256 * 128 * 4);
    float* startbuf = (float*)alloc(256 * 128 * 4);

    auto cvt = [&](const float* src, __hip_bfloat16* dst, int n) {
        int n8 = n / 8;
        f32_to_bf16_k<<<dim3((n8 + 255) / 256), dim3(256), 0, stream>>>(src, dst, n8);
    };
    cvt(x,    xb,  M_TOK * 1024);
    cvt(s_w1, w1b, 512 * 1024);
    cvt(s_w2, w2b, 128 * 512);
    cvt(B_w,  Bwb, 128 * 1024);
    cvt(C_w,  Cwb, 1024 * 128);
    cvt(D_w,  Dwb, 1024 * 1024);
    cvt(g_w,  gwb, 1024 * 1024);

    // A^64 by repeated squaring (fp32 exact) — independent of converts, runs early
    matmul128<<<128, 128, 0, stream>>>(A,  A,  pa);   // A^2
    matmul128<<<128, 128, 0, stream>>>(pa, pa, pb);   // A^4
    matmul128<<<128, 128, 0, stream>>>(pb, pb, pa);   // A^8
    matmul128<<<128, 128, 0, stream>>>(pa, pa, pb);   // A^16
    matmul128<<<128, 128, 0, stream>>>(pb, pb, pa);   // A^32
    matmul128<<<128, 128, 0, stream>>>(pa, pa, pb);   // A^64

    // z1 = silu(x @ s_w1^T + s_b1)
    gemm_silu<<<dim3(512), dim3(256), 0, stream>>>(xb, w1b, s_b1, z1b);
    // u = (x @ B_w^T + B_b) * sigmoid(z1 @ s_w2^T + s_b2)
    gemm_u<<<dim3(256), dim3(256), 0, stream>>>(z1b, w2b, s_b2, xb, Bwb, B_b, ub);

    // chunked scan
    ssm_phase1<<<256, 128, 0, stream>>>(A, ub, Ebuf);
    ssm_phase2<<<8, 128, 0, stream>>>(pb, Ebuf, startbuf);
    ssm_phase3<<<256, 128, 0, stream>>>(A, ub, startbuf, hsb);

    // fused output
    gemm_out<<<dim3(1024), dim3(256), 0, stream>>>(xb, Dwb, gwb, hsb, Cwb,
                                                   D_b, C_b, g_b, out);
}